// Round 1
// 804.999 us; speedup vs baseline: 1.0340x; 1.0340x over previous
//
#include <hip/hip_runtime.h>

// R17: port the two trace GEMMs (B1, B2) from the 128^2 2-barrier m97
// structure (~740 TF, MfmaUtil 32%) to a 256^2 BK=64 8-wave double-buffered
// counted-vmcnt pipeline (T2 swizzle + T3/T4 counted waits + T5 setprio).
//
// Pipeline schedule (provable):
//   K-tile t lives in buf[t&1]; each tile = 2 sub-phases (ksub s=0,1 -> 32 k).
//   phase(t,0): reads buf[t&1].k0   ; stages (t+1,k1) -> buf[(t+1)&1].k1
//   phase(t,1): reads buf[t&1].k1   ; stages (t+2,k0) -> buf[t&1].k0
//   Write-after-read: every staged region's last reader finished >=1 closing
//   barrier (with lgkmcnt(0)) before the stage is issued.
//   Read-availability: vmcnt(8) per phase (= 2 newest half-pairs outstanding)
//   guarantees the NEXT phase's halves have landed; prologue issues 3 pairs
//   then vmcnt(8); tail tapers 8 -> 4 -> 0. vmcnt never drains mid-loop.
// LDS swizzle: source granule gs = g ^ (row&3); ds_read_b128 fragments then
// hit <=2-way bank conflicts (free, m136). global_load_lds dest stays linear
// (uniform base + lane*16), source pre-swizzled (rule #21).
// Numerics: per-element MFMA K-order and epilogue float ops identical to R16
// (Upr bitwise identical; tr differs only by already-nondeterministic atomic
// order) -> absmax should stay 0.009765625.
// g0(next chunk) moved into kt8_b2 blocks' epilogue (grid-stride) so the
// 128 KiB LDS kernel has no low-occupancy streaming tail blocks.

typedef __bf16 bf16;
typedef __bf16 bf16x8 __attribute__((ext_vector_type(8)));
typedef float floatx4 __attribute__((ext_vector_type(4)));

#if defined(__has_builtin)
#if __has_builtin(__builtin_amdgcn_global_load_lds)
#define HAVE_GLL 1
#endif
#endif

typedef __attribute__((address_space(3))) char lds_char_t;
typedef __attribute__((address_space(1))) const char gbl_char_t;

__device__ inline void async_load16(const void* gp, void* lp) {
#ifdef HAVE_GLL
  __builtin_amdgcn_global_load_lds((gbl_char_t*)gp, (lds_char_t*)lp, 16, 0, 0);
#else
  *(bf16x8*)lp = *(const bf16x8*)gp;
#endif
}

// ---------------- 128^2 helpers (forward GEMMs only) ----------------
__device__ inline void stage_async(const bf16* src, long row0, int ld, int kc,
                                   bf16* dst, int wid, int sr8, int cph) {
#pragma unroll
  for (int t = 0; t < 4; ++t) {
    const int r = (wid * 4 + t) * 8 + sr8;
    const int csrc = (cph - r) & 7;
    async_load16(src + (row0 + r) * (size_t)ld + kc + csrc * 8,
                 dst + r * 64 + cph * 8);
  }
}

__device__ inline void mfma_block(const bf16* As, const bf16* Bs,
                                  floatx4 (&acc)[4][4], int wm, int wn,
                                  int l16, int quad) {
#pragma unroll
  for (int ks = 0; ks < 2; ++ks) {
    bf16x8 af[4], bfv[4];
#pragma unroll
    for (int mt = 0; mt < 4; ++mt) {
      const int r = wm * 64 + mt * 16 + l16;
      const int c = (ks * 4 + quad + r) & 7;
      af[mt] = *(const bf16x8*)(As + r * 64 + c * 8);
    }
#pragma unroll
    for (int nt = 0; nt < 4; ++nt) {
      const int r = wn * 64 + nt * 16 + l16;
      const int c = (ks * 4 + quad + r) & 7;
      bfv[nt] = *(const bf16x8*)(Bs + r * 64 + c * 8);
    }
#pragma unroll
    for (int mt = 0; mt < 4; ++mt)
#pragma unroll
      for (int nt = 0; nt < 4; ++nt)
        acc[mt][nt] = __builtin_amdgcn_mfma_f32_16x16x32_bf16(af[mt], bfv[nt], acc[mt][nt], 0, 0, 0);
  }
}

// ---------------- G0 compose body (used by kt_l2g0, chunk 0) ----------------
__device__ inline void g0_body(bf16* G0, const bf16* gw0b, const bf16* d0b,
                               int i0, int ch, int b, int tid) {
  const int nb = ((b >> 9) << 3) + (b & 7);
  const int inner = (b >> 3) & 63;
  if (nb >= ch) return;
  const int e = inner * 256 + tid;
  const int d = e >> 7;
  const int j = (e & 127) << 3;
  const int ig = i0 + nb;
  const int wsel = (d + 1 < 128) ? d + 1 : 127;   // d==127 pad (masked in B2)
  bf16x8 gv = *(const bf16x8*)(gw0b + wsel * 1024 + j);
  bf16x8 dv = *(const bf16x8*)(d0b + (size_t)ig * 1024 + j);
  bf16x8 v;
#pragma unroll
  for (int k = 0; k < 8; ++k) v[k] = (bf16)((float)gv[k] * (float)dv[k]);
  *(bf16x8*)(G0 + ((size_t)nb * 128 + d) * 1024 + j) = v;
}

// ---------------- 256^2 pipelined trace GEMMs ----------------
struct T8 {
  const bf16* A;    // gw1t / gw2t (ld 1024, zero-padded rows)
  const bf16* Bm;   // G0 / Upr   (ld 1024)
  const bf16* sc;   // d1b (960) / d2b (896)
  bf16* Upr;
  const float* gdw;
  float* tr;
  int i0, NT, ch, nTiles;
  // b2-only g0 fusion
  int chn, i0n;
  bf16* G0;
  const bf16* gw0b;
  const bf16* d0b;
};

__device__ __forceinline__ void gemm256(const bf16* Aop, const bf16* Bop,
                                        int m0, int n0, int NT, char* lds,
                                        floatx4 (&acc)[8][4]) {
  const int tid = threadIdx.x;
  const int wid = tid >> 6, lane = tid & 63;
  const int wm = wid & 1, wn = wid >> 1;
  const int quad = lane >> 4, l16 = lane & 15;

  // staging constants: thread covers rows sr and sr+128, granule sg of each
  // 32-k half; source granule pre-swizzled gs = sg ^ (row&3) so that
  // LDS[row][g] holds global granule g ^ (row&3); dest is linear tid*16.
  const int sr = tid >> 2;
  const int sg = tid & 3;
  const int gs = sg ^ (sr & 3);
  const bf16* aS0 = Aop + (size_t)(m0 + sr) * 1024 + gs * 8;
  const bf16* aS1 = aS0 + (size_t)128 * 1024;
  const bf16* bS0 = Bop + (size_t)(n0 + sr) * 1024 + gs * 8;
  const bf16* bS1 = bS0 + (size_t)128 * 1024;
  const int dO0 = tid * 16, dO1 = 8192 + tid * 16;

  // fragment read offsets (elements): row*32 + (quad ^ (row&3))*8, row&3==l16&3
  const int fsw = (quad ^ (l16 & 3)) * 8;
  const int fo  = (wm * 128 + l16) * 32 + fsw;
  const int fob = (wn * 64  + l16) * 32 + fsw;

#define STAGE_PAIR(tt, ss)                                                     \
  {                                                                            \
    char* db = lds + (((tt) & 1) * 65536) + ((ss) * 16384);                    \
    const int kc = (tt) * 64 + (ss) * 32;                                      \
    async_load16(aS0 + kc, db + dO0);                                          \
    async_load16(aS1 + kc, db + dO1);                                          \
    async_load16(bS0 + kc, db + 32768 + dO0);                                  \
    async_load16(bS1 + kc, db + 32768 + dO1);                                  \
  }

#define PHASE(T, S, DOSTAGE, ST, SS, VMSEL)                                    \
  {                                                                            \
    const bf16* Af = (const bf16*)(lds + ((T) & 1) * 65536 + (S) * 16384) + fo;\
    const bf16* Bf = (const bf16*)(lds + ((T) & 1) * 65536 + 32768 +           \
                                   (S) * 16384) + fob;                         \
    bf16x8 af[8], bv[4];                                                       \
    _Pragma("unroll")                                                          \
    for (int mf = 0; mf < 8; ++mf) af[mf] = *(const bf16x8*)(Af + mf * 512);   \
    _Pragma("unroll")                                                          \
    for (int nf = 0; nf < 4; ++nf) bv[nf] = *(const bf16x8*)(Bf + nf * 512);   \
    if (DOSTAGE) STAGE_PAIR(ST, SS);                                           \
    __builtin_amdgcn_sched_barrier(0);                                         \
    {                                                                          \
      const int vms = (VMSEL);                                                 \
      if (vms == 8)      asm volatile("s_waitcnt vmcnt(8)");                   \
      else if (vms == 4) asm volatile("s_waitcnt vmcnt(4)");                   \
      else if (vms == 0) asm volatile("s_waitcnt vmcnt(0)");                   \
    }                                                                          \
    __builtin_amdgcn_sched_barrier(0);                                         \
    __builtin_amdgcn_s_setprio(1);                                             \
    _Pragma("unroll")                                                          \
    for (int mf = 0; mf < 8; ++mf)                                             \
      _Pragma("unroll")                                                        \
      for (int nf = 0; nf < 4; ++nf)                                           \
        acc[mf][nf] = __builtin_amdgcn_mfma_f32_16x16x32_bf16(                 \
            af[mf], bv[nf], acc[mf][nf], 0, 0, 0);                             \
    __builtin_amdgcn_s_setprio(0);                                             \
    asm volatile("s_waitcnt lgkmcnt(0)");                                      \
    __builtin_amdgcn_sched_barrier(0);                                         \
    __builtin_amdgcn_s_barrier();                                              \
    __builtin_amdgcn_sched_barrier(0);                                         \
  }

  // prologue: 3 half-pairs in flight, wait for pair (0,0) only
  STAGE_PAIR(0, 0);
  STAGE_PAIR(0, 1);
  STAGE_PAIR(1, 0);
  __builtin_amdgcn_sched_barrier(0);
  asm volatile("s_waitcnt vmcnt(8)");
  __builtin_amdgcn_sched_barrier(0);
  __builtin_amdgcn_s_barrier();
  __builtin_amdgcn_sched_barrier(0);

#pragma unroll 2
  for (int t = 0; t < NT; ++t) {
    PHASE(t, 0, (t + 1 < NT), t + 1, 1, (t + 1 < NT) ? 8 : 0);
    PHASE(t, 1, (t + 2 < NT), t + 2, 0,
          (t + 2 < NT) ? 8 : ((t + 1 < NT) ? 4 : -1));
  }
#undef PHASE
#undef STAGE_PAIR
}

// B1: Upr[n][m] = d1[ig][m] * (gw1t @ G0)[m][n]  (direct transposed store)
__global__ __launch_bounds__(512, 2) void kt8_b1(T8 p) {
  extern __shared__ __align__(16) char lds[];
  const int mt = (blockIdx.x >> 3) & 3;
  const int nt = ((blockIdx.x >> 5) << 3) | (blockIdx.x & 7);
  if (nt >= p.nTiles) return;

  floatx4 acc[8][4];
#pragma unroll
  for (int a = 0; a < 8; ++a)
#pragma unroll
    for (int b = 0; b < 4; ++b)
#pragma unroll
      for (int r = 0; r < 4; ++r) acc[a][b][r] = 0.0f;

  gemm256(p.A, p.Bm, mt * 256, nt * 256, p.NT, lds, acc);

  const int tid = threadIdx.x;
  const int wid = tid >> 6, lane = tid & 63;
  const int wm = wid & 1, wn = wid >> 1;
  const int quad = lane >> 4, l16 = lane & 15;
  const long nLim = (long)p.ch * 128;
  const int mb = mt * 256 + wm * 128;

#pragma unroll
  for (int nf = 0; nf < 4; ++nf) {
    const long n = (long)nt * 256 + wn * 64 + nf * 16 + l16;
    if (n < nLim) {
      const int ig = p.i0 + (int)(n >> 7);
      const bf16* dp = p.sc + (size_t)ig * 960;
      bf16* urow = p.Upr + (size_t)n * 1024;
#pragma unroll
      for (int mf = 0; mf < 8; ++mf) {
        const int mg = mb + mf * 16 + quad * 4;
        if (mg < 960) {  // cols >=960 never read by B2 (K=960)
          union { bf16 h[4]; uint2 u; } o;
#pragma unroll
          for (int r = 0; r < 4; ++r)
            o.h[r] = (bf16)(acc[mf][nf][r] * (float)dp[mg + r]);
          *(uint2*)(urow + mg) = o.u;
        }
      }
    }
  }
}

// B2: tr[ig] += sum_d ((gw2t @ Upr) * d2 * gdw[:,d]); fused g0(next chunk)
__global__ __launch_bounds__(512, 2) void kt8_b2(T8 p) {
  extern __shared__ __align__(16) char lds[];
  const int mt = (blockIdx.x >> 3) & 3;
  const int nt = ((blockIdx.x >> 5) << 3) | (blockIdx.x & 7);
  const int tid = threadIdx.x;

  if (nt < p.nTiles) {
    floatx4 acc[8][4];
#pragma unroll
    for (int a = 0; a < 8; ++a)
#pragma unroll
      for (int b = 0; b < 4; ++b)
#pragma unroll
        for (int r = 0; r < 4; ++r) acc[a][b][r] = 0.0f;

    gemm256(p.A, p.Bm, mt * 256, nt * 256, p.NT, lds, acc);

    const int wid = tid >> 6, lane = tid & 63;
    const int wm = wid & 1, wn = wid >> 1;
    const int quad = lane >> 4, l16 = lane & 15;
    const long nLim = (long)p.ch * 128;
    const int mb = mt * 256 + wm * 128;

    float s = 0.0f;
#pragma unroll
    for (int nf = 0; nf < 4; ++nf) {
      const long n = (long)nt * 256 + wn * 64 + nf * 16 + l16;
      const int d = (int)(n & 127);
      if (n < nLim && d < 127) {
        const int ig = p.i0 + (int)(n >> 7);
        const bf16* dp = p.sc + (size_t)ig * 896;
#pragma unroll
        for (int mf = 0; mf < 8; ++mf) {
          const int mg = mb + mf * 16 + quad * 4;
          if (mg < 896) {  // gw2t rows >=896 are zero-padded; avoid OOB loads
#pragma unroll
            for (int r = 0; r < 4; ++r) {
              const float w = (float)dp[mg + r] * p.gdw[(mg + r) * 128 + d];
              s += acc[mf][nf][r] * w;
            }
          }
        }
      }
    }
#pragma unroll
    for (int off = 1; off < 64; off <<= 1) s += __shfl_xor(s, off, 64);
    float* red = (float*)lds;  // stage buffers dead after final barrier
    if (lane == 0) red[wid] = s;
    __syncthreads();
    const int igA = p.i0 + nt * 2;
    if (tid == 0)
      atomicAdd(p.tr + igA, red[0] + red[1] + red[2] + red[3]);
    if (tid == 256 && nt * 2 + 1 < p.ch)
      atomicAdd(p.tr + igA + 1, red[4] + red[5] + red[6] + red[7]);
  }

  // g0 for the NEXT chunk: independent of this dispatch's GEMM (B2 reads Upr,
  // g0 writes G0 which B1 of this chunk has finished reading).
  if (p.chn > 0) {
    const size_t V = (size_t)p.chn * 16384;  // vec8 units
    for (size_t v = (size_t)blockIdx.x * 512 + tid; v < V;
         v += (size_t)gridDim.x * 512) {
      const int j = ((int)(v & 127)) << 3;
      const size_t rest = v >> 7;
      const int d = (int)(rest & 127);
      const int nb = (int)(rest >> 7);
      const int wsel = (d + 1 < 128) ? d + 1 : 127;
      bf16x8 gv = *(const bf16x8*)(p.gw0b + wsel * 1024 + j);
      bf16x8 dv = *(const bf16x8*)(p.d0b + (size_t)(p.i0n + nb) * 1024 + j);
      bf16x8 o;
#pragma unroll
      for (int k = 0; k < 8; ++k) o[k] = (bf16)((float)gv[k] * (float)dv[k]);
      *(bf16x8*)(p.G0 + ((size_t)nb * 128 + d) * 1024 + j) = o;
    }
  }
}

// ---------------- forward GEMMs (unchanged) ----------------
struct FArgs {
  const bf16* A; int lda;
  const bf16* Bt; int ldb;
  const float* bias;
  bf16* C; int ldc;
  bf16* D; int ldd;
  float* outF; int ldo;
  int K; int realN; int gridX;
};

template <int ACT>
__device__ inline void fwd_body(const FArgs& p, int bx, bf16* As, bf16* Bs) {
  const int tid  = threadIdx.x;
  const int wid  = tid >> 6, lane = tid & 63;
  const int wm   = wid & 1, wn = wid >> 1;
  const int quad = lane >> 4, l16 = lane & 15;
  const int sr8  = lane >> 3, cph = lane & 7;
  const int m0   = (bx % p.gridX) * 128;
  const int bn0  = (bx / p.gridX) * 128;

  floatx4 acc[4][4];
#pragma unroll
  for (int a = 0; a < 4; ++a)
#pragma unroll
    for (int b = 0; b < 4; ++b)
#pragma unroll
      for (int r = 0; r < 4; ++r) acc[a][b][r] = 0.0f;

  for (int kc = 0; kc < p.K; kc += 64) {
    stage_async(p.A, m0, p.lda, kc, As, wid, sr8, cph);
    stage_async(p.Bt, bn0, p.ldb, kc, Bs, wid, sr8, cph);
    __syncthreads();
    mfma_block(As, Bs, acc, wm, wn, l16, quad);
    __syncthreads();
  }

#pragma unroll
  for (int nt = 0; nt < 4; ++nt) {
    const int ng = bn0 + wn * 64 + nt * 16 + l16;
    const float bv = (ng < p.realN) ? p.bias[ng] : 0.0f;
#pragma unroll
    for (int mt = 0; mt < 4; ++mt)
#pragma unroll
      for (int r = 0; r < 4; ++r) {
        const int i = m0 + wm * 64 + mt * 16 + quad * 4 + r;
        const float v = acc[mt][nt][r] + bv;
        if (ACT) {
          const float t = tanhf(v);
          p.C[(size_t)i * p.ldc + ng] = (ng < p.realN) ? (bf16)t : (bf16)0.0f;
          if (p.D && ng < p.realN)
            p.D[(size_t)i * p.ldd + ng] = (bf16)(1.0f - t * t);
        } else if (ng < p.realN) {
          p.outF[(size_t)i * p.ldo + ng] = v;
        }
      }
  }
}

__global__ __launch_bounds__(256) void kt_fwd2(FArgs a, int na, FArgs b) {
  __shared__ __align__(16) bf16 As[8192];
  __shared__ __align__(16) bf16 Bs[8192];
  const int bx = blockIdx.x;
  if (bx < na) fwd_body<1>(a, bx, As, Bs);
  else         fwd_body<1>(b, bx - na, As, Bs);
}

__global__ __launch_bounds__(256) void kt_l2g0(FArgs a, int na, bf16* G0,
                                               const bf16* gw0b, const bf16* d0b,
                                               int i0, int ch) {
  __shared__ __align__(16) bf16 As[8192];
  __shared__ __align__(16) bf16 Bs[8192];
  const int bx = blockIdx.x;
  if (bx < na) fwd_body<1>(a, bx, As, Bs);
  else         g0_body(G0, gw0b, d0b, i0, ch, bx - na, threadIdx.x);
}

__global__ __launch_bounds__(256) void kt_dxgdot(FArgs a, int na,
                                                 const bf16* e1b, const float* bdw,
                                                 const float* bdb, float* gf,
                                                 float* gout) {
  __shared__ __align__(16) bf16 As[8192];
  __shared__ __align__(16) bf16 Bs[8192];
  const int bx = blockIdx.x;
  if (bx < na) { fwd_body<0>(a, bx, As, Bs); return; }
  const int i = (bx - na) * 4 + (threadIdx.x >> 6);
  const int lane = threadIdx.x & 63;
  float s = 0.0f;
  for (int k = lane; k < 448; k += 64) s += (float)e1b[(size_t)i * 512 + k] * bdw[k];
#pragma unroll
  for (int off = 32; off > 0; off >>= 1) s += __shfl_down(s, off, 64);
  if (lane == 0) {
    const float v = s + bdb[0];
    gf[i] = v;
    gout[i] = v;
  }
}

// ---------------- fused prep with LDS-tiled transposes ----------------
struct PArgs {
  const float *gw0, *gw1, *gw2, *gdw, *bw0, *bw1, *pt, *x;
  bf16 *gw0b, *gw0t, *gw1t, *gw2t, *gdwt, *bw0t, *bw1t, *Xg, *Xb;
};

__device__ inline void tpose_tile(bf16* dst, const float* src, int R, int C,
                                  int ldd, int tile, int tilesX, float* tl,
                                  int tid) {
  const int r0 = (tile % tilesX) * 64;
  const int c0 = (tile / tilesX) * 64;
  const int tx = tid & 63, ty0 = tid >> 6;
#pragma unroll
  for (int i = 0; i < 16; ++i) {
    const int ty = ty0 + i * 4;
    const int r = r0 + ty, c = c0 + tx;
    tl[ty * 65 + tx] = (r < R && c < C) ? src[(size_t)r * C + c] : 0.0f;
  }
  __syncthreads();
#pragma unroll
  for (int i = 0; i < 16; ++i) {
    const int ty = ty0 + i * 4;
    dst[(size_t)(c0 + ty) * ldd + r0 + tx] = (bf16)tl[tx * 65 + ty];
  }
}

__global__ __launch_bounds__(256) void kt_prep(PArgs p) {
  __shared__ float tl[64 * 65];
  int b = blockIdx.x;
  const int t = threadIdx.x;
  if (b < 512) { p.gw0b[b * 256 + t] = (bf16)p.gw0[b * 256 + t]; return; }
  b -= 512;
  if (b < 768) {  // build Xg/Xb
    const int idx = b * 256 + t;
    const int i = idx / 192, c = idx % 192;
    const float s = p.pt[0];
    float vb;
    if (c == 0) vb = s;
    else if (c <= 128) vb = p.x[i * 128 + c - 1];
    else vb = 0.0f;
    p.Xb[i * 192 + c] = (bf16)vb;
    if (c < 128) p.Xg[i * 128 + c] = (bf16)((c == 0) ? s : p.x[i * 128 + c - 1]);
    return;
  }
  b -= 768;
  if (b < 32)  { tpose_tile(p.gw0t, p.gw0, 128, 1024, 128, b, 2, tl, t);  return; }
  b -= 32;
  if (b < 256) { tpose_tile(p.gw1t, p.gw1, 1024, 960, 1024, b, 16, tl, t); return; }
  b -= 256;
  if (b < 256) { tpose_tile(p.gw2t, p.gw2, 960, 896, 1024, b, 16, tl, t); return; }
  b -= 256;
  if (b < 32)  { tpose_tile(p.gdwt, p.gdw, 896, 128, 1024, b, 16, tl, t); return; }
  b -= 32;
  if (b < 24)  { tpose_tile(p.bw0t, p.bw0, 129, 512, 192, b, 3, tl, t);  return; }
  b -= 24;
  if (b < 64)  { tpose_tile(p.bw1t, p.bw1, 512, 448, 512, b, 8, tl, t);  return; }
}

__global__ __launch_bounds__(256) void kt_fin(const float* gf, const float* tr,
                                              const float* pp, float* dp) {
  const int i = blockIdx.x * 256 + threadIdx.x;
  if (i < 1024) dp[i] = gf[i] - pp[i] * tr[i];
}

extern "C" void kernel_launch(void* const* d_in, const int* in_sizes, int n_in,
                              void* d_out, int out_size, void* d_ws, size_t ws_size,
                              hipStream_t stream) {
  const float* pt  = (const float*)d_in[0];
  const float* x   = (const float*)d_in[1];
  const float* pp  = (const float*)d_in[3];
  const float* gw0 = (const float*)d_in[4];
  const float* gb0 = (const float*)d_in[5];
  const float* gw1 = (const float*)d_in[6];
  const float* gb1 = (const float*)d_in[7];
  const float* gw2 = (const float*)d_in[8];
  const float* gb2 = (const float*)d_in[9];
  const float* gdw = (const float*)d_in[10];
  const float* gdb = (const float*)d_in[11];
  const float* bw0 = (const float*)d_in[12];
  const float* bb0 = (const float*)d_in[13];
  const float* bw1 = (const float*)d_in[14];
  const float* bb1 = (const float*)d_in[15];
  const float* bdw = (const float*)d_in[16];
  const float* bdb = (const float*)d_in[17];
  float* out = (float*)d_out;

  static bool s_attr = false;
  if (!s_attr) {
    hipFuncSetAttribute((const void*)kt8_b1,
                        hipFuncAttributeMaxDynamicSharedMemorySize, 131072);
    hipFuncSetAttribute((const void*)kt8_b2,
                        hipFuncAttributeMaxDynamicSharedMemorySize, 131072);
    s_attr = true;
  }

  char* w = (char*)d_ws;
  size_t used = 0;
  auto alloc = [&](size_t nbytes) -> void* {
    void* r = w + used;
    used += (nbytes + 255) & ~(size_t)255;
    return r;
  };
  bf16* gw0b = (bf16*)alloc((size_t)128 * 1024 * 2);
  bf16* gw0t = (bf16*)alloc((size_t)1024 * 128 * 2);
  bf16* gw1t = (bf16*)alloc((size_t)1024 * 1024 * 2);
  bf16* gw2t = (bf16*)alloc((size_t)1024 * 1024 * 2);
  bf16* gdwt = (bf16*)alloc((size_t)128 * 1024 * 2);
  bf16* bw0t = (bf16*)alloc((size_t)512 * 192 * 2);
  bf16* bw1t = (bf16*)alloc((size_t)512 * 512 * 2);
  bf16* Xg   = (bf16*)alloc((size_t)1024 * 128 * 2);
  bf16* Xb   = (bf16*)alloc((size_t)1024 * 192 * 2);
  bf16* h0b  = (bf16*)alloc((size_t)1024 * 1024 * 2);
  bf16* h1b  = (bf16*)alloc((size_t)1024 * 1024 * 2);
  bf16* h2b  = (bf16*)alloc((size_t)1024 * 1024 * 2);
  bf16* e0b  = (bf16*)alloc((size_t)1024 * 512 * 2);
  bf16* e1b  = (bf16*)alloc((size_t)1024 * 512 * 2);
  bf16* d0b  = (bf16*)alloc((size_t)1024 * 1024 * 2);
  bf16* d1b  = (bf16*)alloc((size_t)1024 * 960 * 2);
  bf16* d2b  = (bf16*)alloc((size_t)1024 * 896 * 2);
  float* gf  = (float*)alloc(1024 * 4);
  float* tr  = (float*)alloc(1024 * 4);

  const size_t perSample = (size_t)128 * 1024 * 2;     // 256 KB
  size_t avail = (ws_size > used) ? ws_size - used : 0;
  int CH = (int)(avail / (2 * perSample));
  if (CH > 256) CH = 256;   // 4 chunks; G0+Upr = 128 MB stays L3-resident
  if (CH >= 2) CH &= ~1;    // even CH -> all chunks even -> clean 256-row tiles
  if (CH < 1) CH = 1;
  bf16* G0  = (bf16*)alloc((size_t)CH * perSample);
  bf16* Upr = (bf16*)(w + used);

  hipMemsetAsync(tr, 0, 1024 * 4, stream);

  {
    PArgs a{gw0, gw1, gw2, gdw, bw0, bw1, pt, x,
            gw0b, gw0t, gw1t, gw2t, gdwt, bw0t, bw1t, Xg, Xb};
    kt_prep<<<dim3(1944), 256, 0, stream>>>(a);
  }

  // F1 = L0 ∪ e0
  {
    FArgs a{}; a.A = Xg; a.lda = 128; a.Bt = gw0t; a.ldb = 128; a.bias = gb0;
    a.C = h0b; a.ldc = 1024; a.D = d0b; a.ldd = 1024; a.K = 128; a.realN = 1024;
    a.gridX = 8;   // 64 blocks
    FArgs b{}; b.A = Xb; b.lda = 192; b.Bt = bw0t; b.ldb = 192; b.bias = bb0;
    b.C = e0b; b.ldc = 512; b.K = 192; b.realN = 512; b.gridX = 8;  // 32 blocks
    kt_fwd2<<<dim3(96), 256, 0, stream>>>(a, 64, b);
  }
  // F2 = L1 ∪ e1
  {
    FArgs a{}; a.A = h0b; a.lda = 1024; a.Bt = gw1t; a.ldb = 1024; a.bias = gb1;
    a.C = h1b; a.ldc = 1024; a.D = d1b; a.ldd = 960; a.K = 1024; a.realN = 960;
    a.gridX = 8;   // 64 blocks
    FArgs b{}; b.A = e0b; b.lda = 512; b.Bt = bw1t; b.ldb = 512; b.bias = bb1;
    b.C = e1b; b.ldc = 512; b.K = 512; b.realN = 448; b.gridX = 8;  // 32 blocks
    kt_fwd2<<<dim3(96), 256, 0, stream>>>(a, 64, b);
  }
  // F3 = L2 ∪ g0(chunk 0)
  const int ch0  = (1024 < CH) ? 1024 : CH;
  const int ch08 = (ch0 + 7) & ~7;
  {
    FArgs a{}; a.A = h1b; a.lda = 1024; a.Bt = gw2t; a.ldb = 1024; a.bias = gb2;
    a.C = h2b; a.ldc = 1024; a.D = d2b; a.ldd = 896; a.K = 1024; a.realN = 896;
    a.gridX = 8;   // 56 blocks (offset 56 ≡ 0 mod 8 keeps g0's XCD phase)
    kt_l2g0<<<dim3(56 + ch08 * 64), 256, 0, stream>>>(a, 56, G0, gw0b, d0b, 0, ch0);
  }
  // F4 = dx ∪ gdot
  {
    FArgs a{}; a.A = h2b; a.lda = 1024; a.Bt = gdwt; a.ldb = 1024; a.bias = gdb;
    a.outF = out; a.ldo = 128; a.K = 896; a.realN = 128; a.gridX = 8;  // 8 blocks
    kt_dxgdot<<<dim3(8 + 256), 256, 0, stream>>>(a, 8, e1b, bdw, bdb, gf, out + 131072);
  }

  for (int i0 = 0; i0 < 1024; i0 += CH) {
    const int ch  = (1024 - i0 < CH) ? (1024 - i0) : CH;
    const int nTiles = (ch * 128 + 255) >> 8;       // = ch/2 for even ch
    const int nT8 = (nTiles + 7) & ~7;
    {  // B1: U' = D1 * (gw1^T @ G0), M pad 1024, K=1024
      T8 a{}; a.A = gw1t; a.Bm = G0; a.sc = d1b; a.Upr = Upr; a.i0 = i0;
      a.NT = 16; a.ch = ch; a.nTiles = nTiles;
      kt8_b1<<<dim3(nT8 * 4), 512, 131072, stream>>>(a);
    }
    {  // B2 (trace reduce) ∪ g0(next chunk)
      const int i0n = i0 + CH;
      const int chn = (i0n < 1024) ? ((1024 - i0n < CH) ? (1024 - i0n) : CH) : 0;
      T8 a{}; a.A = gw2t; a.Bm = Upr; a.sc = d2b; a.gdw = gdw; a.tr = tr;
      a.i0 = i0; a.NT = 15; a.ch = ch; a.nTiles = nTiles;
      a.chn = chn; a.i0n = i0n; a.G0 = G0; a.gw0b = gw0b; a.d0b = d0b;
      kt8_b2<<<dim3(nT8 * 4), 512, 131072, stream>>>(a);
    }
  }

  kt_fin<<<dim3(4), 256, 0, stream>>>(gf, tr, pp, out + 132096);
}